// Round 1
// baseline (261.402 us; speedup 1.0000x reference)
//
#include <hip/hip_runtime.h>
#include <math.h>

#define N_T 32768
#define L 65536
#define BATCH 64
#define NEV 8
#define NROOM 16
#define DGATE 128
#define NC 8
#define NCP 9
#define NRW 8

__device__ __forceinline__ float2 cmul(float2 a, float2 b) {
    return make_float2(a.x * b.x - a.y * b.y, a.x * b.y + a.y * b.x);
}

__device__ __forceinline__ unsigned fkey(float f) {
    int i = __float_as_int(f);
    return (unsigned)(i ^ ((i >> 31) | 0x80000000));
}

// ---- gating: room softmax weights + mix + init max keys ----
__global__ void k_prep(const float* __restrict__ g, const float* __restrict__ w_room,
                       const float* __restrict__ b_room, const float* __restrict__ w_mix,
                       const float* __restrict__ b_mix,
                       float* __restrict__ wroom, float* __restrict__ mixv,
                       unsigned* __restrict__ mxkey) {
    int b = threadIdx.x;
    if (b >= BATCH) return;
    float logits[NROOM];
    for (int r = 0; r < NROOM; r++) logits[r] = b_room[r];
    float acc_mix = b_mix[0];
    for (int d = 0; d < DGATE; d++) {
        float gv = g[b * DGATE + d];
        for (int r = 0; r < NROOM; r++) logits[r] += gv * w_room[d * NROOM + r];
        acc_mix += gv * w_mix[d];
    }
    float m = logits[0];
    for (int r = 1; r < NROOM; r++) m = fmaxf(m, logits[r]);
    float s = 0.f;
    for (int r = 0; r < NROOM; r++) { logits[r] = expf(logits[r] - m); s += logits[r]; }
    float inv = 1.f / s;
    for (int r = 0; r < NROOM; r++) wroom[b * NROOM + r] = logits[r] * inv;
    mixv[b] = 1.f / (1.f + expf(-acc_mix));
    mxkey[b] = 0u;
}

// ---- build dry (scatter-add as gather) + spread into complex buffer ----
__global__ void k_dry(const float* __restrict__ events, const int* __restrict__ indices,
                      float* __restrict__ dryf, float2* __restrict__ C) {
    int gid = blockIdx.x * blockDim.x + threadIdx.x;
    int b = gid >> 16;
    int t = gid & (L - 1);
    float v = 0.f;
    if (t < N_T) {
        const float* eb = events + (size_t)b * NEV * N_T;
        const int* ib = indices + b * NEV;
#pragma unroll
        for (int e = 0; e < NEV; e++) {
            int st = ib[e] * 256;
            int n = t - st;
            if (n >= 0) v += eb[e * N_T + n];
        }
        dryf[(size_t)b * N_T + t] = v;
    }
    C[(size_t)b * L + t] = make_float2(v, 0.f);
}

__global__ void k_spread_rooms(const float* __restrict__ rooms, float2* __restrict__ Crooms) {
    int gid = blockIdx.x * blockDim.x + threadIdx.x;
    int r = gid >> 16;
    int t = gid & (L - 1);
    float v = (t < N_T) ? rooms[(size_t)r * N_T + t] : 0.f;
    Crooms[(size_t)r * L + t] = make_float2(v, 0.f);
}

// ---- four-step FFT, column pass (length-256 FFT over n2, stride 256) ----
// fwd: FFT(-) then twiddle e^{-2pi i n1 k2 / 65536}, store back.
// inv: FFT(+) over k2, output n2 natural; store real*(1/L) for n2<128 into wet.
template <bool INV>
__global__ void k_fft_col(float2* __restrict__ C, float* __restrict__ wet) {
    __shared__ float2 bufA[256 * NCP];
    __shared__ float2 bufB[256 * NCP];
    __shared__ float2 tw[128];
    int t = threadIdx.x;
    int a = blockIdx.x >> 5;
    int c0 = (blockIdx.x & 31) * NC;
    float2* base = C + (size_t)a * L;

    if (t < 128) {
        float ang = -6.2831853071795864769f * (float)t / 256.0f;
        float sv, cv;
        __sincosf(ang, &sv, &cv);
        tw[t] = make_float2(cv, INV ? -sv : sv);
    }
    for (int k = t; k < 256 * NC; k += 256) {
        int c = k & (NC - 1);
        int e = k >> 3;
        bufA[e * NCP + c] = base[(c0 + c) + (e << 8)];
    }
    __syncthreads();
    float2* src = bufA;
    float2* dst = bufB;
    for (int s = 1; s <= 128; s <<= 1) {
        for (int w = t; w < 128 * NC; w += 256) {
            int c = w & (NC - 1);
            int j = w >> 3;
            int ps = j & ~(s - 1);
            float2 x0 = src[j * NCP + c];
            float2 x1 = src[(j + 128) * NCP + c];
            float2 wp = tw[ps];
            dst[(j + ps) * NCP + c] = make_float2(x0.x + x1.x, x0.y + x1.y);
            dst[(j + ps + s) * NCP + c] = cmul(make_float2(x0.x - x1.x, x0.y - x1.y), wp);
        }
        __syncthreads();
        float2* tmp = src; src = dst; dst = tmp;
    }
    if (!INV) {
        for (int k = t; k < 256 * NC; k += 256) {
            int c = k & (NC - 1);
            int k2 = k >> 3;
            int n1 = c0 + c;
            float ang = -6.2831853071795864769f * (float)(n1 * k2) / 65536.0f;
            float sv, cv;
            __sincosf(ang, &sv, &cv);
            base[n1 + (k2 << 8)] = cmul(src[k2 * NCP + c], make_float2(cv, sv));
        }
    } else {
        for (int k = t; k < 256 * NC; k += 256) {
            int c = k & (NC - 1);
            int n2 = k >> 3;
            if (n2 < 128) {
                float2 v = src[n2 * NCP + c];
                wet[(size_t)a * N_T + (c0 + c) + (n2 << 8)] = v.x * (1.0f / 65536.0f);
            }
        }
    }
}

// ---- four-step FFT, row pass (length-256 FFT over contiguous n1) ----
// fwd: plain FFT(-), store back (scrambled output order).
// inv: FFT(+) over k1, then twiddle e^{+2pi i n1 k2 / 65536}, store back.
template <bool INV>
__global__ void k_fft_row(float2* __restrict__ C) {
    __shared__ float2 bufA[NRW * 256];
    __shared__ float2 bufB[NRW * 256];
    __shared__ float2 tw[128];
    int t = threadIdx.x;
    int a = blockIdx.x >> 5;
    int r0 = (blockIdx.x & 31) * NRW;
    float2* chunk = C + (size_t)a * L + (size_t)r0 * 256;

    if (t < 128) {
        float ang = -6.2831853071795864769f * (float)t / 256.0f;
        float sv, cv;
        __sincosf(ang, &sv, &cv);
        tw[t] = make_float2(cv, INV ? -sv : sv);
    }
    for (int k = t; k < NRW * 256; k += 256) bufA[k] = chunk[k];
    __syncthreads();
    float2* src = bufA;
    float2* dst = bufB;
    for (int s = 1; s <= 128; s <<= 1) {
        for (int w = t; w < NRW * 128; w += 256) {
            int rr = w >> 7;
            int j = w & 127;
            int ps = j & ~(s - 1);
            int rb = rr << 8;
            float2 x0 = src[rb + j];
            float2 x1 = src[rb + j + 128];
            float2 wp = tw[ps];
            dst[rb + j + ps] = make_float2(x0.x + x1.x, x0.y + x1.y);
            dst[rb + j + ps + s] = cmul(make_float2(x0.x - x1.x, x0.y - x1.y), wp);
        }
        __syncthreads();
        float2* tmp = src; src = dst; dst = tmp;
    }
    if (!INV) {
        for (int k = t; k < NRW * 256; k += 256) chunk[k] = src[k];
    } else {
        for (int k = t; k < NRW * 256; k += 256) {
            int rr = k >> 8;
            int n1 = k & 255;
            int k2 = r0 + rr;
            float ang = 6.2831853071795864769f * (float)(n1 * k2) / 65536.0f;
            float sv, cv;
            __sincosf(ang, &sv, &cv);
            chunk[k] = cmul(src[k], make_float2(cv, sv));
        }
    }
}

// ---- pointwise: W = D * (sum_r wroom[b][r] * Rhat[r]) in scrambled order ----
__global__ void k_pointwise(float2* __restrict__ C, const float* __restrict__ wroom) {
    int gid = blockIdx.x * blockDim.x + threadIdx.x;
    int b = gid >> 16;
    int j = gid & (L - 1);
    const float2* R = C + (size_t)BATCH * L;
    const float* wr = wroom + b * NROOM;
    float2 kk = make_float2(0.f, 0.f);
#pragma unroll
    for (int r = 0; r < NROOM; r++) {
        float2 rv = R[(size_t)r * L + j];
        float w = wr[r];
        kk.x += w * rv.x;
        kk.y += w * rv.y;
    }
    size_t idx = (size_t)b * L + j;
    C[idx] = cmul(C[idx], kk);
}

// ---- out = mix*wet + (1-mix)*dry, per-row max via atomic on monotone keys ----
__global__ void k_out1(float* __restrict__ out, const float* __restrict__ dryf,
                       const float* __restrict__ mixv, unsigned* __restrict__ mxkey) {
    int gid = blockIdx.x * blockDim.x + threadIdx.x;
    int b = gid >> 15;
    int tt = gid & (N_T - 1);
    float mix = mixv[b];
    float w = out[(size_t)b * N_T + tt];  // wet was written into d_out
    float d = dryf[(size_t)b * N_T + tt];
    float o = mix * w + (1.f - mix) * d;
    out[(size_t)b * N_T + tt] = o;
    __shared__ float red[256];
    red[threadIdx.x] = o;
    __syncthreads();
    for (int off = 128; off > 0; off >>= 1) {
        if (threadIdx.x < off) red[threadIdx.x] = fmaxf(red[threadIdx.x], red[threadIdx.x + off]);
        __syncthreads();
    }
    if (threadIdx.x == 0) atomicMax(mxkey + b, fkey(red[0]));
}

__global__ void k_out2(float* __restrict__ out, const unsigned* __restrict__ mxkey) {
    int gid = blockIdx.x * blockDim.x + threadIdx.x;
    int b = gid >> 15;
    int tt = gid & (N_T - 1);
    unsigned k = mxkey[b];
    int i = (k & 0x80000000u) ? (int)(k ^ 0x80000000u) : ~(int)k;
    float mx = __int_as_float(i);
    out[(size_t)b * N_T + tt] = out[(size_t)b * N_T + tt] / (mx + 1e-8f);
}

extern "C" void kernel_launch(void* const* d_in, const int* in_sizes, int n_in,
                              void* d_out, int out_size, void* d_ws, size_t ws_size,
                              hipStream_t stream) {
    const float* events = (const float*)d_in[0];
    const int* indices = (const int*)d_in[1];
    const float* g      = (const float*)d_in[2];
    const float* rooms  = (const float*)d_in[3];
    const float* w_room = (const float*)d_in[4];
    const float* b_room = (const float*)d_in[5];
    const float* w_mix  = (const float*)d_in[6];
    const float* b_mix  = (const float*)d_in[7];
    float* out = (float*)d_out;

    char* ws = (char*)d_ws;
    float2* C = (float2*)ws;  // [80][65536] complex: 0..63 dry, 64..79 rooms
    size_t off = (size_t)(BATCH + NROOM) * L * sizeof(float2);
    float* dryf = (float*)(ws + off);
    off += (size_t)BATCH * N_T * sizeof(float);
    float* wroom = (float*)(ws + off);
    off += BATCH * NROOM * sizeof(float);
    float* mixv = (float*)(ws + off);
    off += BATCH * sizeof(float);
    unsigned* mxkey = (unsigned*)(ws + off);

    k_prep<<<1, 64, 0, stream>>>(g, w_room, b_room, w_mix, b_mix, wroom, mixv, mxkey);
    k_dry<<<BATCH * L / 256, 256, 0, stream>>>(events, indices, dryf, C);
    k_spread_rooms<<<NROOM * L / 256, 256, 0, stream>>>(rooms, C + (size_t)BATCH * L);
    k_fft_col<false><<<(BATCH + NROOM) * 32, 256, 0, stream>>>(C, nullptr);
    k_fft_row<false><<<(BATCH + NROOM) * 32, 256, 0, stream>>>(C);
    k_pointwise<<<BATCH * L / 256, 256, 0, stream>>>(C, wroom);
    k_fft_row<true><<<BATCH * 32, 256, 0, stream>>>(C);
    k_fft_col<true><<<BATCH * 32, 256, 0, stream>>>(C, out);  // writes wet into d_out
    k_out1<<<BATCH * N_T / 256, 256, 0, stream>>>(out, dryf, mixv, mxkey);
    k_out2<<<BATCH * N_T / 256, 256, 0, stream>>>(out, mxkey);
}

// Round 2
// 173.012 us; speedup vs baseline: 1.5109x; 1.5109x over previous
//
#include <hip/hip_runtime.h>
#include <math.h>

#define N_T 32768
#define L 65536
#define BATCH 64
#define NEV 8
#define NROOM 16
#define DGATE 128
#define NC 8
#define NCP 9
#define NRW 8
#define TWO_PI 6.2831853071795864769f

__device__ __forceinline__ float2 cmul(float2 a, float2 b) {
    return make_float2(a.x * b.x - a.y * b.y, a.x * b.y + a.y * b.x);
}

// ---- gating: room softmax weights + mix ----
__global__ void k_prep(const float* __restrict__ g, const float* __restrict__ w_room,
                       const float* __restrict__ b_room, const float* __restrict__ w_mix,
                       const float* __restrict__ b_mix,
                       float* __restrict__ wroom, float* __restrict__ mixv) {
    int b = threadIdx.x;
    if (b >= BATCH) return;
    float logits[NROOM];
    for (int r = 0; r < NROOM; r++) logits[r] = b_room[r];
    float acc_mix = b_mix[0];
    for (int d = 0; d < DGATE; d++) {
        float gv = g[b * DGATE + d];
        for (int r = 0; r < NROOM; r++) logits[r] += gv * w_room[d * NROOM + r];
        acc_mix += gv * w_mix[d];
    }
    float m = logits[0];
    for (int r = 1; r < NROOM; r++) m = fmaxf(m, logits[r]);
    float s = 0.f;
    for (int r = 0; r < NROOM; r++) { logits[r] = expf(logits[r] - m); s += logits[r]; }
    float inv = 1.f / s;
    for (int r = 0; r < NROOM; r++) wroom[b * NROOM + r] = logits[r] * inv;
    mixv[b] = 1.f / (1.f + expf(-acc_mix));
}

// ---- build dry (scatter-add as gather), float4, + spread into complex buffer ----
__global__ void k_dry(const float* __restrict__ events, const int* __restrict__ indices,
                      float* __restrict__ dryf, float2* __restrict__ C) {
    int gid = blockIdx.x * blockDim.x + threadIdx.x;  // BATCH * L/4
    int b = gid >> 14;
    int q = gid & 16383;
    int t0 = q << 2;
    float4* Cv = (float4*)(C + (size_t)b * L + t0);
    if (t0 < N_T) {
        const float* eb = events + (size_t)b * NEV * N_T;
        const int* ib = indices + b * NEV;
        float4 v = make_float4(0.f, 0.f, 0.f, 0.f);
#pragma unroll
        for (int e = 0; e < NEV; e++) {
            int st = ib[e] << 8;
            int n = t0 - st;
            if (n >= 0) {  // st,t0 both mult of 4 -> branch uniform over the 4 lanes' elems
                float4 ev = *(const float4*)(eb + e * N_T + n);
                v.x += ev.x; v.y += ev.y; v.z += ev.z; v.w += ev.w;
            }
        }
        *(float4*)(dryf + (size_t)b * N_T + t0) = v;
        Cv[0] = make_float4(v.x, 0.f, v.y, 0.f);
        Cv[1] = make_float4(v.z, 0.f, v.w, 0.f);
    } else {
        Cv[0] = make_float4(0.f, 0.f, 0.f, 0.f);
        Cv[1] = make_float4(0.f, 0.f, 0.f, 0.f);
    }
}

__global__ void k_spread_rooms(const float* __restrict__ rooms, float2* __restrict__ Crooms) {
    int gid = blockIdx.x * blockDim.x + threadIdx.x;  // NROOM * L/4
    int r = gid >> 14;
    int q = gid & 16383;
    int t0 = q << 2;
    float4* Cv = (float4*)(Crooms + (size_t)r * L + t0);
    if (t0 < N_T) {
        float4 v = *(const float4*)(rooms + (size_t)r * N_T + t0);
        Cv[0] = make_float4(v.x, 0.f, v.y, 0.f);
        Cv[1] = make_float4(v.z, 0.f, v.w, 0.f);
    } else {
        Cv[0] = make_float4(0.f, 0.f, 0.f, 0.f);
        Cv[1] = make_float4(0.f, 0.f, 0.f, 0.f);
    }
}

// ---- four-step FFT, column pass (length-256 FFT over n2, stride 256) ----
template <bool INV>
__global__ void k_fft_col(float2* __restrict__ C, float* __restrict__ wet) {
    __shared__ float2 bufA[256 * NCP];
    __shared__ float2 bufB[256 * NCP];
    __shared__ float2 tw[128];
    int t = threadIdx.x;
    int a = blockIdx.x >> 5;
    int c0 = (blockIdx.x & 31) * NC;
    float2* base = C + (size_t)a * L;

    if (t < 128) {
        float ang = -TWO_PI * (float)t / 256.0f;
        float sv, cv;
        __sincosf(ang, &sv, &cv);
        tw[t] = make_float2(cv, INV ? -sv : sv);
    }
    for (int k = t; k < 256 * NC; k += 256) {
        int c = k & (NC - 1);
        int e = k >> 3;
        bufA[e * NCP + c] = base[(c0 + c) + (e << 8)];
    }
    __syncthreads();
    float2* src = bufA;
    float2* dst = bufB;
    for (int s = 1; s <= 128; s <<= 1) {
        for (int w = t; w < 128 * NC; w += 256) {
            int c = w & (NC - 1);
            int j = w >> 3;
            int ps = j & ~(s - 1);
            float2 x0 = src[j * NCP + c];
            float2 x1 = src[(j + 128) * NCP + c];
            float2 wp = tw[ps];
            dst[(j + ps) * NCP + c] = make_float2(x0.x + x1.x, x0.y + x1.y);
            dst[(j + ps + s) * NCP + c] = cmul(make_float2(x0.x - x1.x, x0.y - x1.y), wp);
        }
        __syncthreads();
        float2* tmp = src; src = dst; dst = tmp;
    }
    if (!INV) {
        for (int k = t; k < 256 * NC; k += 256) {
            int c = k & (NC - 1);
            int k2 = k >> 3;
            int n1 = c0 + c;
            int ph = (n1 * k2) & (L - 1);      // exact integer phase, small arg for sincos
            float ang = -TWO_PI * (float)ph * (1.0f / 65536.0f);
            float sv, cv;
            __sincosf(ang, &sv, &cv);
            base[n1 + (k2 << 8)] = cmul(src[k2 * NCP + c], make_float2(cv, sv));
        }
    } else {
        for (int k = t; k < 256 * NC; k += 256) {
            int c = k & (NC - 1);
            int n2 = k >> 3;
            if (n2 < 128) {
                float2 v = src[n2 * NCP + c];
                wet[(size_t)a * N_T + (c0 + c) + (n2 << 8)] = v.x * (1.0f / 65536.0f);
            }
        }
    }
}

// ---- four-step FFT, row pass (length-256 FFT over contiguous n1) ----
template <bool INV>
__global__ void k_fft_row(float2* __restrict__ C) {
    __shared__ float2 bufA[NRW * 256];
    __shared__ float2 bufB[NRW * 256];
    __shared__ float2 tw[128];
    int t = threadIdx.x;
    int a = blockIdx.x >> 5;
    int r0 = (blockIdx.x & 31) * NRW;
    float2* chunk = C + (size_t)a * L + (size_t)r0 * 256;

    if (t < 128) {
        float ang = -TWO_PI * (float)t / 256.0f;
        float sv, cv;
        __sincosf(ang, &sv, &cv);
        tw[t] = make_float2(cv, INV ? -sv : sv);
    }
    for (int k = t; k < NRW * 256; k += 256) bufA[k] = chunk[k];
    __syncthreads();
    float2* src = bufA;
    float2* dst = bufB;
    for (int s = 1; s <= 128; s <<= 1) {
        for (int w = t; w < NRW * 128; w += 256) {
            int rr = w >> 7;
            int j = w & 127;
            int ps = j & ~(s - 1);
            int rb = rr << 8;
            float2 x0 = src[rb + j];
            float2 x1 = src[rb + j + 128];
            float2 wp = tw[ps];
            dst[rb + j + ps] = make_float2(x0.x + x1.x, x0.y + x1.y);
            dst[rb + j + ps + s] = cmul(make_float2(x0.x - x1.x, x0.y - x1.y), wp);
        }
        __syncthreads();
        float2* tmp = src; src = dst; dst = tmp;
    }
    if (!INV) {
        for (int k = t; k < NRW * 256; k += 256) chunk[k] = src[k];
    } else {
        for (int k = t; k < NRW * 256; k += 256) {
            int rr = k >> 8;
            int n1 = k & 255;
            int k2 = r0 + rr;
            int ph = (n1 * k2) & (L - 1);
            float ang = TWO_PI * (float)ph * (1.0f / 65536.0f);
            float sv, cv;
            __sincosf(ang, &sv, &cv);
            chunk[k] = cmul(src[k], make_float2(cv, sv));
        }
    }
}

// ---- pointwise: D *= sum_r wroom[b][r]*Rhat[r], rooms staged in registers ----
__global__ void k_pw(float2* __restrict__ C, const float* __restrict__ wroom) {
    __shared__ float wr[BATCH * NROOM];
    int tid = threadIdx.x;
    for (int i = tid; i < BATCH * NROOM; i += 256) wr[i] = wroom[i];
    int jb = blockIdx.x & 255;
    int bg = blockIdx.x >> 8;   // 0..1
    int j = jb * 256 + tid;
    const float2* R = C + (size_t)BATCH * L;
    float2 rr[NROOM];
#pragma unroll
    for (int r = 0; r < NROOM; r++) rr[r] = R[(size_t)r * L + j];
    __syncthreads();
    for (int b = bg * 32; b < bg * 32 + 32; b++) {
        float2 kk = make_float2(0.f, 0.f);
#pragma unroll
        for (int r = 0; r < NROOM; r++) {
            float w = wr[b * NROOM + r];
            kk.x += w * rr[r].x;
            kk.y += w * rr[r].y;
        }
        size_t idx = (size_t)b * L + j;
        C[idx] = cmul(C[idx], kk);
    }
}

// ---- out = mix*wet + (1-mix)*dry; per-block partial max (NO atomics) ----
__global__ void k_mix(float* __restrict__ out, const float* __restrict__ dryf,
                      const float* __restrict__ mixv, float* __restrict__ partial) {
    int blk = blockIdx.x;          // 64*32
    int b = blk >> 5;
    int ch = blk & 31;
    size_t base = (size_t)b * N_T + ch * 1024 + threadIdx.x * 4;
    float4 w = *(const float4*)(out + base);
    float4 d = *(const float4*)(dryf + base);
    float mix = mixv[b];
    float om = 1.f - mix;
    float4 o;
    o.x = mix * w.x + om * d.x;
    o.y = mix * w.y + om * d.y;
    o.z = mix * w.z + om * d.z;
    o.w = mix * w.w + om * d.w;
    *(float4*)(out + base) = o;
    float m = fmaxf(fmaxf(o.x, o.y), fmaxf(o.z, o.w));
#pragma unroll
    for (int off = 32; off > 0; off >>= 1) m = fmaxf(m, __shfl_down(m, off));
    __shared__ float sm[4];
    if ((threadIdx.x & 63) == 0) sm[threadIdx.x >> 6] = m;
    __syncthreads();
    if (threadIdx.x == 0)
        partial[blk] = fmaxf(fmaxf(sm[0], sm[1]), fmaxf(sm[2], sm[3]));
}

__global__ void k_norm(float* __restrict__ out, const float* __restrict__ partial) {
    int blk = blockIdx.x;
    int b = blk >> 5;
    int ch = blk & 31;
    __shared__ float smx;
    if (threadIdx.x < 32) {
        float p = partial[b * 32 + threadIdx.x];
#pragma unroll
        for (int off = 16; off > 0; off >>= 1) p = fmaxf(p, __shfl_down(p, off, 32));
        if (threadIdx.x == 0) smx = p;
    }
    __syncthreads();
    float inv = 1.f / (smx + 1e-8f);
    size_t base = (size_t)b * N_T + ch * 1024 + threadIdx.x * 4;
    float4 o = *(const float4*)(out + base);
    o.x *= inv; o.y *= inv; o.z *= inv; o.w *= inv;
    *(float4*)(out + base) = o;
}

extern "C" void kernel_launch(void* const* d_in, const int* in_sizes, int n_in,
                              void* d_out, int out_size, void* d_ws, size_t ws_size,
                              hipStream_t stream) {
    const float* events = (const float*)d_in[0];
    const int* indices = (const int*)d_in[1];
    const float* g      = (const float*)d_in[2];
    const float* rooms  = (const float*)d_in[3];
    const float* w_room = (const float*)d_in[4];
    const float* b_room = (const float*)d_in[5];
    const float* w_mix  = (const float*)d_in[6];
    const float* b_mix  = (const float*)d_in[7];
    float* out = (float*)d_out;

    char* ws = (char*)d_ws;
    float2* C = (float2*)ws;  // [80][65536] complex: 0..63 dry, 64..79 rooms
    size_t off = (size_t)(BATCH + NROOM) * L * sizeof(float2);
    float* dryf = (float*)(ws + off);
    off += (size_t)BATCH * N_T * sizeof(float);
    float* wroom = (float*)(ws + off);
    off += BATCH * NROOM * sizeof(float);
    float* mixv = (float*)(ws + off);
    off += BATCH * sizeof(float);
    float* partial = (float*)(ws + off);

    k_prep<<<1, 64, 0, stream>>>(g, w_room, b_room, w_mix, b_mix, wroom, mixv);
    k_dry<<<BATCH * (L / 4) / 256, 256, 0, stream>>>(events, indices, dryf, C);
    k_spread_rooms<<<NROOM * (L / 4) / 256, 256, 0, stream>>>(rooms, C + (size_t)BATCH * L);
    k_fft_col<false><<<(BATCH + NROOM) * 32, 256, 0, stream>>>(C, nullptr);
    k_fft_row<false><<<(BATCH + NROOM) * 32, 256, 0, stream>>>(C);
    k_pw<<<512, 256, 0, stream>>>(C, wroom);
    k_fft_row<true><<<BATCH * 32, 256, 0, stream>>>(C);
    k_fft_col<true><<<BATCH * 32, 256, 0, stream>>>(C, out);  // wet -> d_out
    k_mix<<<BATCH * 32, 256, 0, stream>>>(out, dryf, mixv, partial);
    k_norm<<<BATCH * 32, 256, 0, stream>>>(out, partial);
}